// Round 1
// baseline (350.936 us; speedup 1.0000x reference)
//
#include <hip/hip_runtime.h>
#include <math.h>

// Problem constants (from setup_inputs)
#define N_DET 512
#define K_ANN 100
#define MH    28
#define MW    28
#define NPIX  (MH * MW)     // 784
#define IMH   800
#define IMW   800
#define IOU_THRESH 0.5f
#define EPS_F 1e-7f

// Main fused kernel: one block per detection.
//  - threads 0..99: IOU vs each annotation
//  - block argmax reduce (first-index tie-break, matching jnp.argmax)
//  - if max_iou >= 0.5: bilinear crop_and_resize + masks gather + |diff| sum
//  - one atomicAdd per block into ws[0] (sum) and ws[1] (valid count)
__global__ __launch_bounds__(256) void maskloss_main(
    const float* __restrict__ det,    // (512,4)  x1,y1,x2,y2
    const float* __restrict__ masks,  // (512,28,28,100)
    const float* __restrict__ ann,    // (100,4)
    const float* __restrict__ mt,     // (100,800,800)
    float* __restrict__ ws)           // ws[0]=sum, ws[1]=count (pre-zeroed)
{
    __shared__ float sv[256];
    __shared__ int   si[256];

    const int n   = blockIdx.x;
    const int tid = threadIdx.x;

    // Detection box (all threads read the same 4 floats; L1 broadcast)
    const float dx1 = det[n * 4 + 0];
    const float dy1 = det[n * 4 + 1];
    const float dx2 = det[n * 4 + 2];
    const float dy2 = det[n * 4 + 3];

    // ---- IOU: thread k handles annotation k (K=100 < 256) ----
    float best = -1.0f;
    int   bidx = 0x7FFFFFFF;
    if (tid < K_ANN) {
        const float ax1 = ann[tid * 4 + 0];
        const float ay1 = ann[tid * 4 + 1];
        const float ax2 = ann[tid * 4 + 2];
        const float ay2 = ann[tid * 4 + 3];
        const float area_k = (ax2 - ax1) * (ay2 - ay1);
        float iw = fminf(dx2, ax2) - fmaxf(dx1, ax1);
        float ih = fminf(dy2, ay2) - fmaxf(dy1, ay1);
        iw = fmaxf(iw, 0.0f);
        ih = fmaxf(ih, 0.0f);
        const float inter = iw * ih;
        const float ua = (dx2 - dx1) * (dy2 - dy1) + area_k - inter;
        best = inter / fmaxf(ua, EPS_F);
        bidx = tid;
    }

    // ---- block argmax reduce; ties -> smaller index (jnp.argmax) ----
    sv[tid] = best;
    si[tid] = bidx;
    __syncthreads();
    for (int s = 128; s > 0; s >>= 1) {
        if (tid < s) {
            const float ov = sv[tid + s];
            const int   oi = si[tid + s];
            if (ov > sv[tid] || (ov == sv[tid] && oi < si[tid])) {
                sv[tid] = ov;
                si[tid] = oi;
            }
        }
        __syncthreads();
    }
    const float max_iou = sv[0];
    const int   k       = si[0];
    __syncthreads();  // before sv[] reuse below

    // Invalid detection contributes exactly 0 (diff * valid with valid=0)
    if (max_iou < IOU_THRESH) return;

    // ---- crop_and_resize boxes = [y1/H, x1/W, y2/H, x2/W] ----
    const float by1 = dy1 / (float)IMH;
    const float bx1 = dx1 / (float)IMW;
    const float by2 = dy2 / (float)IMH;
    const float bx2 = dx2 / (float)IMW;

    const float* __restrict__ img = mt + (size_t)k * (IMH * IMW);
    const float* __restrict__ msk = masks + (size_t)n * NPIX * K_ANN + k;

    float local = 0.0f;
    for (int p = tid; p < NPIX; p += 256) {
        const int i = p / MW;
        const int j = p - i * MW;
        const float gy = (float)i * (1.0f / (float)(MH - 1));
        const float gx = (float)j * (1.0f / (float)(MW - 1));
        const float in_y = (by1 + (by2 - by1) * gy) * (float)(IMH - 1);
        const float in_x = (bx1 + (bx2 - bx1) * gx) * (float)(IMW - 1);
        const bool vy = (in_y >= 0.0f) && (in_y <= (float)(IMH - 1));
        const bool vx = (in_x >= 0.0f) && (in_x <= (float)(IMW - 1));
        const float y0f = floorf(in_y);
        const float x0f = floorf(in_x);
        const float yf = in_y - y0f;
        const float xf = in_x - x0f;
        int y0i = (int)y0f;
        int x0i = (int)x0f;
        y0i = min(max(y0i, 0), IMH - 1);
        x0i = min(max(x0i, 0), IMW - 1);
        const int y1i = min(y0i + 1, IMH - 1);
        const int x1i = min(x0i + 1, IMW - 1);

        const float v00 = img[y0i * IMW + x0i];
        const float v01 = img[y0i * IMW + x1i];
        const float v10 = img[y1i * IMW + x0i];
        const float v11 = img[y1i * IMW + x1i];
        const float top = v00 + (v01 - v00) * xf;
        const float bot = v10 + (v11 - v10) * xf;
        float outv = top + (bot - top) * yf;
        outv = (vy && vx) ? outv : 0.0f;

        const float msel = msk[(size_t)p * K_ANN];  // masks[n, i, j, k]
        local += fabsf(msel - outv);
    }

    // ---- block sum reduce ----
    sv[tid] = local;
    __syncthreads();
    for (int s = 128; s > 0; s >>= 1) {
        if (tid < s) sv[tid] += sv[tid + s];
        __syncthreads();
    }
    if (tid == 0) {
        atomicAdd(&ws[0], sv[0]);
        atomicAdd(&ws[1], 1.0f);
    }
}

__global__ void maskloss_final(const float* __restrict__ ws,
                               float* __restrict__ out)
{
    const float s = ws[0];
    const float c = ws[1];
    const float divisor = fmaxf(c * (float)NPIX, 1.0f);
    out[0] = s / divisor;
}

extern "C" void kernel_launch(void* const* d_in, const int* in_sizes, int n_in,
                              void* d_out, int out_size, void* d_ws, size_t ws_size,
                              hipStream_t stream) {
    const float* det   = (const float*)d_in[0];  // detections (1,512,4)
    const float* masks = (const float*)d_in[1];  // masks (1,512,28,28,100)
    const float* ann   = (const float*)d_in[2];  // annotations (1,100,4)
    const float* mt    = (const float*)d_in[3];  // masks_target (1,100,800,800)
    float* out = (float*)d_out;
    float* acc = (float*)d_ws;

    // ws is poisoned to 0xAA before every timed launch — zero the accumulators.
    hipMemsetAsync(acc, 0, 2 * sizeof(float), stream);

    maskloss_main<<<N_DET, 256, 0, stream>>>(det, masks, ann, mt, acc);
    maskloss_final<<<1, 1, 0, stream>>>(acc, out);
}

// Round 2
// 349.280 us; speedup vs baseline: 1.0047x; 1.0047x over previous
//
#include <hip/hip_runtime.h>
#include <math.h>

// Problem constants (from setup_inputs)
#define N_DET 512
#define K_ANN 100
#define MH    28
#define MW    28
#define NPIX  (MH * MW)     // 784
#define IMH   800
#define IMW   800
#define BLOCKS_PER_DET 3    // 3 blocks x 256 thr = 768 >= 784 with a tiny stride tail
#define IOU_THRESH 0.5f
#define EPS_F 1e-7f

// ws layout (first 8 bytes zeroed each launch):
//   wsi[0] : valid-detection count (int)
//   wsf[1] : running |diff| sum (float)
//   wsi[2 + i], i in [0,512) : compacted packed entries (n << 7) | k

// ---------------- Kernel 1: IOU + argmax + compaction ----------------
__global__ __launch_bounds__(128) void iou_argmax(
    const float* __restrict__ det,   // (512,4) x1,y1,x2,y2
    const float* __restrict__ ann,   // (100,4)
    int* __restrict__ wsi)
{
    __shared__ float sv[128];
    __shared__ int   si[128];

    const int n   = blockIdx.x;
    const int tid = threadIdx.x;

    const float dx1 = det[n * 4 + 0];
    const float dy1 = det[n * 4 + 1];
    const float dx2 = det[n * 4 + 2];
    const float dy2 = det[n * 4 + 3];

    float best = -1.0f;
    int   bidx = 0x7FFFFFFF;
    if (tid < K_ANN) {
        const float ax1 = ann[tid * 4 + 0];
        const float ay1 = ann[tid * 4 + 1];
        const float ax2 = ann[tid * 4 + 2];
        const float ay2 = ann[tid * 4 + 3];
        const float area_k = (ax2 - ax1) * (ay2 - ay1);
        float iw = fminf(dx2, ax2) - fmaxf(dx1, ax1);
        float ih = fminf(dy2, ay2) - fmaxf(dy1, ay1);
        iw = fmaxf(iw, 0.0f);
        ih = fmaxf(ih, 0.0f);
        const float inter = iw * ih;
        const float ua = (dx2 - dx1) * (dy2 - dy1) + area_k - inter;
        best = inter / fmaxf(ua, EPS_F);
        bidx = tid;
    }

    sv[tid] = best;
    si[tid] = bidx;
    __syncthreads();
    // argmax reduce; ties -> smaller index (jnp.argmax semantics)
    for (int s = 64; s > 0; s >>= 1) {
        if (tid < s) {
            const float ov = sv[tid + s];
            const int   oi = si[tid + s];
            if (ov > sv[tid] || (ov == sv[tid] && oi < si[tid])) {
                sv[tid] = ov;
                si[tid] = oi;
            }
        }
        __syncthreads();
    }

    if (tid == 0 && sv[0] >= IOU_THRESH) {
        const int pos = atomicAdd(&wsi[0], 1);
        wsi[2 + pos] = (n << 7) | si[0];
    }
}

// ---------------- Kernel 2: bilinear crop + mask gather + |diff| sum ----------------
__global__ __launch_bounds__(256) void pixel_loss(
    const float* __restrict__ det,    // (512,4)
    const float* __restrict__ masks,  // (512,28,28,100)
    const float* __restrict__ mt,     // (100,800,800)
    const int*   __restrict__ wsi,
    float*       __restrict__ wsf)
{
    const int b   = blockIdx.x;
    const int idx = b / BLOCKS_PER_DET;
    const int rem = b - idx * BLOCKS_PER_DET;

    const int count = wsi[0];
    if (idx >= count) return;

    const int packed = wsi[2 + idx];
    const int n = packed >> 7;
    const int k = packed & 127;

    const float dx1 = det[n * 4 + 0];
    const float dy1 = det[n * 4 + 1];
    const float dx2 = det[n * 4 + 2];
    const float dy2 = det[n * 4 + 3];

    // boxes = [y1/H, x1/W, y2/H, x2/W]
    const float by1 = dy1 / (float)IMH;
    const float bx1 = dx1 / (float)IMW;
    const float by2 = dy2 / (float)IMH;
    const float bx2 = dx2 / (float)IMW;

    const float* __restrict__ img = mt + (size_t)k * (IMH * IMW);
    const float* __restrict__ msk = masks + (size_t)n * NPIX * K_ANN + k;

    float local = 0.0f;
    // block `rem` covers pixels rem*256 + tid, strided by 768 (only rem==0 wraps, 16 px tail)
    for (int p = rem * 256 + threadIdx.x; p < NPIX; p += BLOCKS_PER_DET * 256) {
        const int i = p / MW;
        const int j = p - i * MW;
        const float gy = (float)i * (1.0f / (float)(MH - 1));
        const float gx = (float)j * (1.0f / (float)(MW - 1));
        const float in_y = (by1 + (by2 - by1) * gy) * (float)(IMH - 1);
        const float in_x = (bx1 + (bx2 - bx1) * gx) * (float)(IMW - 1);
        const bool vy = (in_y >= 0.0f) && (in_y <= (float)(IMH - 1));
        const bool vx = (in_x >= 0.0f) && (in_x <= (float)(IMW - 1));
        const float y0f = floorf(in_y);
        const float x0f = floorf(in_x);
        const float yf = in_y - y0f;
        const float xf = in_x - x0f;
        int y0i = (int)y0f;
        int x0i = (int)x0f;
        y0i = min(max(y0i, 0), IMH - 1);
        x0i = min(max(x0i, 0), IMW - 1);
        const int y1i = min(y0i + 1, IMH - 1);
        const int x1i = min(x0i + 1, IMW - 1);

        const float v00 = img[y0i * IMW + x0i];
        const float v01 = img[y0i * IMW + x1i];
        const float v10 = img[y1i * IMW + x0i];
        const float v11 = img[y1i * IMW + x1i];
        const float top = v00 + (v01 - v00) * xf;
        const float bot = v10 + (v11 - v10) * xf;
        float outv = top + (bot - top) * yf;
        outv = (vy && vx) ? outv : 0.0f;

        const float msel = msk[(size_t)p * K_ANN];  // masks[n, i, j, k], stride-100 gather
        local += fabsf(msel - outv);
    }

    // wave shuffle reduce (64-lane) then cross-wave via LDS
    for (int off = 32; off > 0; off >>= 1)
        local += __shfl_down(local, off);

    __shared__ float wsum[4];
    const int wave = threadIdx.x >> 6;
    const int lane = threadIdx.x & 63;
    if (lane == 0) wsum[wave] = local;
    __syncthreads();
    if (threadIdx.x == 0)
        atomicAdd(&wsf[1], (wsum[0] + wsum[1]) + (wsum[2] + wsum[3]));
}

// ---------------- Kernel 3: finalize ----------------
__global__ void maskloss_final(const int* __restrict__ wsi,
                               const float* __restrict__ wsf,
                               float* __restrict__ out)
{
    const float c = (float)wsi[0];
    const float divisor = fmaxf(c * (float)NPIX, 1.0f);
    out[0] = wsf[1] / divisor;
}

extern "C" void kernel_launch(void* const* d_in, const int* in_sizes, int n_in,
                              void* d_out, int out_size, void* d_ws, size_t ws_size,
                              hipStream_t stream) {
    const float* det   = (const float*)d_in[0];  // detections (1,512,4)
    const float* masks = (const float*)d_in[1];  // masks (1,512,28,28,100)
    const float* ann   = (const float*)d_in[2];  // annotations (1,100,4)
    const float* mt    = (const float*)d_in[3];  // masks_target (1,100,800,800)
    float* out = (float*)d_out;
    int*   wsi = (int*)d_ws;
    float* wsf = (float*)d_ws;

    // ws is poisoned to 0xAA before every timed launch — zero count + sum.
    hipMemsetAsync(d_ws, 0, 2 * sizeof(float), stream);

    iou_argmax<<<N_DET, 128, 0, stream>>>(det, ann, wsi);
    pixel_loss<<<N_DET * BLOCKS_PER_DET, 256, 0, stream>>>(det, masks, mt, wsi, wsf);
    maskloss_final<<<1, 1, 0, stream>>>(wsi, wsf, out);
}